// Round 7
// baseline (610.179 us; speedup 1.0000x reference)
//
#include <hip/hip_runtime.h>
#include <hip/hip_bf16.h>

// Problem: CausalSelfAttention  B=4, T=2048, C=1024, NH=16, HD=64
// Pipeline: prep (x->bf16 + W_attn^T, merged) -> QKV GEMM (256x128 tile,
// 512 thr, single-buf gload_lds, XOR-swizzled LDS via pre-swizzled global
// source, 3 blocks/CU full residency, fused V-transpose epilogue) -> MFMA
// flash causal attention v8 (single 64-row q-tiles, grid 2048 heavy-first,
// 6 blocks/CU, dbuf K/V, MFMA row-sums, XCD-local heads) -> W_proj^T ->
// proj GEMM (128^2 dbuf, unchanged control).
//
// Workspace: 64 MiB in 4 regions of 16 MiB with lifetime overlap:
//   R0 qb   [8192][1024] bf16      live: gemm1 -> attn;  WtP parked here for gemm2
//   R1 kb   [8192][1024] bf16      live: gemm1 -> attn
//   R2 vtb  [B][NH][64][T] bf16    live: gemm1 (fused transpose) -> attn
//   R3 xb   [8192][1024] bf16      live: prep -> gemm1;  yb (attn out) overwrites
// d_out[0:6MiB] parks WtA (bf16 W_attn^T) until gemm1 done; gemm2 overwrites.

typedef __bf16 bf16;
typedef __bf16 bf16x4 __attribute__((ext_vector_type(4)));
typedef __bf16 bf16x8 __attribute__((ext_vector_type(8)));
typedef float  f32x4  __attribute__((ext_vector_type(4)));

#define MFMA16(a, b, c) __builtin_amdgcn_mfma_f32_16x16x32_bf16((a), (b), (c), 0, 0, 0)

// global -> LDS direct copy, 16B per lane. LDS dest is WAVE-UNIFORM base;
// HW adds lane*16B. Global src is per-lane.
#define GLOAD16(g, l)                                                 \
    __builtin_amdgcn_global_load_lds(                                 \
        (const __attribute__((address_space(1))) void*)(g),           \
        (__attribute__((address_space(3))) void*)(l), 16, 0, 0)

static constexpr int Bsz = 4;
static constexpr int T   = 2048;
static constexpr int Cc  = 1024;
static constexpr int NH  = 16;
static constexpr int HD  = 64;
static constexpr int C3  = 3 * Cc;   // 3072

// ---------------------------------------------------------------------------
// Prep kernel: blocks [0, 4096) convert x fp32 -> bf16 (8 elems/thread);
// blocks [4096, 4096+3072) transpose+downcast W_attn [1024][3072] -> WtA
// [3072][1024]. Both block types use 256 threads.
// ---------------------------------------------------------------------------
__global__ void prep(const float* __restrict__ x, bf16* __restrict__ xb,
                     const float* __restrict__ W_attn, bf16* __restrict__ WtA) {
    const int bid = blockIdx.x;
    const int tid = threadIdx.x;
    if (bid < 4096) {
        size_t i = ((size_t)bid * 256 + tid) * 8;
        f32x4 a0 = *(const f32x4*)(x + i);
        f32x4 a1 = *(const f32x4*)(x + i + 4);
        bf16x8 v;
#pragma unroll
        for (int e = 0; e < 4; ++e) { v[e] = (bf16)a0[e]; v[e + 4] = (bf16)a1[e]; }
        *(bf16x8*)(xb + i) = v;
    } else {
        __shared__ float tile[32][33];
        const int tb = bid - 4096;
        const int bx = (tb % (C3 / 32)) * 32;   // col base in W_attn (3072)
        const int by = (tb / (C3 / 32)) * 32;   // row base in W_attn (1024)
        const int tx = tid & 31, ty = tid >> 5; // (32, 8)
#pragma unroll
        for (int i = 0; i < 32; i += 8)
            tile[ty + i][tx] = W_attn[(size_t)(by + ty + i) * C3 + bx + tx];
        __syncthreads();
#pragma unroll
        for (int i = 0; i < 32; i += 8)
            WtA[(size_t)(bx + ty + i) * Cc + by + tx] = (bf16)tile[tx][ty + i];
    }
}

// ---------------------------------------------------------------------------
// 32x32 tiled transpose + downcast: in fp32 [R][Ccols] -> out bf16 [Ccols][R]
// (used for W_proj after attention frees R0)
// ---------------------------------------------------------------------------
__global__ void transpose_f32_bf16(const float* __restrict__ in, bf16* __restrict__ out,
                                   int R, int Ccols) {
    __shared__ float tile[32][33];
    int bx = blockIdx.x * 32;
    int by = blockIdx.y * 32;
    int tx = threadIdx.x, ty = threadIdx.y;  // block (32, 8)
#pragma unroll
    for (int i = 0; i < 32; i += 8)
        tile[ty + i][tx] = in[(size_t)(by + ty + i) * Ccols + bx + tx];
    __syncthreads();
#pragma unroll
    for (int i = 0; i < 32; i += 8)
        out[(size_t)(bx + ty + i) * R + by + tx] = (bf16)tile[tx][ty + i];
}

// ---------------------------------------------------------------------------
// GEMM1: qkv = xb(bf16) @ WtA^T + bias. 256x128 tile, 512 threads (8 waves,
// 4m x 2n, per-wave 64x64 output), single-buffered gload_lds staging,
// XOR-SWIZZLED LDS (T2, both-sides form):
//   gload_lds writes linearly, so the swizzle is applied by permuting the
//   GLOBAL source per lane: staged col16 = (lane&7) ^ (lane>>3)  (row&7 ==
//   lane>>3 for this geometry, constant across r and k0). Frag reads XOR
//   the 16B-chunk index with (l16&7): physical (row, c16) holds logical
//   col c16 ^ (row&7) on both sides -> involution, bijective, and lanes
//   0..15 spread over 8 slots -> 2-way max (free) instead of 16-way.
// launch_bounds(512,6) -> 3 blocks/CU -> all 768 blocks co-resident (no tail).
// q/k thirds scattered to qo/ko [M][1024]; v third written TRANSPOSED per
// head directly to vt [B][NH][HD][T] (fused Tv).
// ---------------------------------------------------------------------------
__global__ __launch_bounds__(512, 6)
void gemm_qkv(const bf16* __restrict__ A, const bf16* __restrict__ Bt,
              const float* __restrict__ bias,
              bf16* __restrict__ qo, bf16* __restrict__ ko, bf16* __restrict__ vt,
              int M, int N, int K) {
    constexpr int BM = 256, BN = 128, BK = 64;
    __shared__ bf16 As[BM * BK];   // 32 KB
    __shared__ bf16 Bs[BN * BK];   // 16 KB

    const int tid  = threadIdx.x;
    const int wave = tid >> 6, lane = tid & 63;
    const int quad = lane >> 4, l16 = lane & 15;
    const int wm = wave >> 1, wn = wave & 1;     // 4m x 2n wave grid
    const int m0 = blockIdx.x * BM, n0 = blockIdx.y * BN;

    f32x4 acc[4][4] = {};

    // staging: thread's LDS slot is row = wave*8 + (lane>>3) + r*64,
    // c16 = lane&7 (16B chunks). Pre-swizzled global col16 = (lane&7)^(lane>>3).
    const int lrow = lane >> 3;
    const int lcol = ((lane & 7) ^ lrow) * 8;    // swizzled source column (elems)
    const bf16* Ab = A  + (size_t)(m0 + wave * 8 + lrow) * K + lcol;
    const bf16* Bb = Bt + (size_t)(n0 + wave * 8 + lrow) * K + lcol;
    const int wofs = wave * 512;
    const int sxo = l16 & 7;                     // read-side XOR (row&7)

    for (int k0 = 0; k0 < K; k0 += BK) {
#pragma unroll
        for (int r = 0; r < 4; ++r)
            GLOAD16(Ab + (size_t)(r * 64) * K + k0, As + wofs + r * 4096);
#pragma unroll
        for (int r = 0; r < 2; ++r)
            GLOAD16(Bb + (size_t)(r * 64) * K + k0, Bs + wofs + r * 4096);
        __syncthreads();   // drains vmcnt: tile ready

#pragma unroll
        for (int ks = 0; ks < 2; ++ks) {
            bf16x8 af[4], bfr[4];
#pragma unroll
            for (int i = 0; i < 4; ++i)
                af[i] = *(const bf16x8*)(&As[(wm * 64 + i * 16 + l16) * BK
                                             + (((ks * 4 + quad) ^ sxo) << 3)]);
#pragma unroll
            for (int j = 0; j < 4; ++j)
                bfr[j] = *(const bf16x8*)(&Bs[(wn * 64 + j * 16 + l16) * BK
                                              + (((ks * 4 + quad) ^ sxo) << 3)]);
#pragma unroll
            for (int i = 0; i < 4; ++i)
#pragma unroll
                for (int j = 0; j < 4; ++j)
                    acc[i][j] = MFMA16(af[i], bfr[j], acc[i][j]);
        }
        __syncthreads();   // all reads done before next stage
    }

    // epilogue: third = n0>>10 (BN=128 divides 1024 evenly)
    const int which = n0 >> 10;
    const int nc0 = n0 & 1023;
    if (which < 2) {
        bf16* dst = which ? ko : qo;
#pragma unroll
        for (int j = 0; j < 4; ++j) {
            int colg = n0 + wn * 64 + j * 16 + l16;
            int coll = nc0 + wn * 64 + j * 16 + l16;
            float bv = bias[colg];
#pragma unroll
            for (int i = 0; i < 4; ++i) {
                int rowb = m0 + wm * 64 + i * 16 + quad * 4;
#pragma unroll
                for (int r = 0; r < 4; ++r)
                    dst[(size_t)(rowb + r) * Cc + coll] = (bf16)(acc[i][j][r] + bv);
            }
        }
    } else {
        // v third: write transposed per head -> vt[b][h][d][t]; the 4 acc rows
        // per frag are consecutive t -> contiguous bf16x4 store.
#pragma unroll
        for (int j = 0; j < 4; ++j) {
            int colg = n0 + wn * 64 + j * 16 + l16;
            int coll = nc0 + wn * 64 + j * 16 + l16;
            int h = coll >> 6, d = coll & 63;
            float bv = bias[colg];
            bf16* vhead_d = vt + ((size_t)h * HD + d) * T;   // b-offset added below
#pragma unroll
            for (int i = 0; i < 4; ++i) {
                int rowb = m0 + wm * 64 + i * 16 + quad * 4;
                int b = rowb >> 11;          // T = 2048; BM=256 tiles never cross b
                int t = rowb & 2047;         // multiple of 4
                bf16x4 pk;
#pragma unroll
                for (int r = 0; r < 4; ++r) pk[r] = (bf16)(acc[i][j][r] + bv);
                *(bf16x4*)(vhead_d + (size_t)b * NH * HD * T + t) = pk;
            }
        }
    }
}

// ---------------------------------------------------------------------------
// GEMM2: out(fp32) = A(bf16) @ Bt^T + bias. 128^2 dbuf gload_lds
// (unchanged — control for the gemm_qkv swizzle experiment).
// ---------------------------------------------------------------------------
__global__ __launch_bounds__(256)
void gemm_bt(const bf16* __restrict__ A, const bf16* __restrict__ Bt,
             const float* __restrict__ bias, float* __restrict__ C,
             int M, int N, int K) {
    constexpr int BM = 128, BN = 128, BK = 64;
    __shared__ bf16 As[2][BM * BK];
    __shared__ bf16 Bs[2][BN * BK];

    const int tid  = threadIdx.x;
    const int wave = tid >> 6, lane = tid & 63;
    const int quad = lane >> 4, l16 = lane & 15;
    const int wm = wave & 1, wn = wave >> 1;
    const int m0 = blockIdx.x * BM, n0 = blockIdx.y * BN;

    f32x4 acc[4][4] = {};

    const int lrow = lane >> 3;
    const int lcol = (lane & 7) * 8;
    const bf16* Ab = A  + (size_t)(m0 + wave * 8 + lrow) * K + lcol;
    const bf16* Bb = Bt + (size_t)(n0 + wave * 8 + lrow) * K + lcol;
    const int wofs = wave * 512;

#pragma unroll
    for (int r = 0; r < 4; ++r) {
        GLOAD16(Ab + (size_t)r * 32 * K, As[0] + wofs + r * 2048);
        GLOAD16(Bb + (size_t)r * 32 * K, Bs[0] + wofs + r * 2048);
    }

    int cur = 0;
    for (int k0 = 0; k0 < K; k0 += BK) {
        __syncthreads();
        if (k0 + BK < K) {
#pragma unroll
            for (int r = 0; r < 4; ++r) {
                GLOAD16(Ab + (size_t)r * 32 * K + k0 + BK, As[cur ^ 1] + wofs + r * 2048);
                GLOAD16(Bb + (size_t)r * 32 * K + k0 + BK, Bs[cur ^ 1] + wofs + r * 2048);
            }
        }
        const bf16* Asc = As[cur];
        const bf16* Bsc = Bs[cur];
#pragma unroll
        for (int ks = 0; ks < 2; ++ks) {
            bf16x8 af[4], bfr[4];
#pragma unroll
            for (int i = 0; i < 4; ++i)
                af[i] = *(const bf16x8*)(&Asc[(wm * 64 + i * 16 + l16) * BK + ks * 32 + quad * 8]);
#pragma unroll
            for (int j = 0; j < 4; ++j)
                bfr[j] = *(const bf16x8*)(&Bsc[(wn * 64 + j * 16 + l16) * BK + ks * 32 + quad * 8]);
#pragma unroll
            for (int i = 0; i < 4; ++i)
#pragma unroll
                for (int j = 0; j < 4; ++j)
                    acc[i][j] = MFMA16(af[i], bfr[j], acc[i][j]);
        }
        cur ^= 1;
    }

#pragma unroll
    for (int j = 0; j < 4; ++j) {
        int col = n0 + wn * 64 + j * 16 + l16;
        float bv = bias[col];
#pragma unroll
        for (int i = 0; i < 4; ++i) {
            int rowb = m0 + wm * 64 + i * 16 + quad * 4;
#pragma unroll
            for (int r = 0; r < 4; ++r)
                C[(size_t)(rowb + r) * N + col] = acc[i][j][r] + bv;
        }
    }
}

// ---------------------------------------------------------------------------
// MFMA flash causal attention v8 (unchanged): single 64-row q-tile per block,
// grid 2048 heavy-first, 6 blocks/CU, dbuf K/V, 1 barrier/tile, MFMA
// row-sums, XCD-local heads, setprio on compute.
// ---------------------------------------------------------------------------
__global__ __launch_bounds__(256, 6)
void attn_fused(const bf16* __restrict__ qb, const bf16* __restrict__ kb,
                const bf16* __restrict__ vtb, bf16* __restrict__ y) {
    constexpr int LKD = 72;             // K-tile row pitch  (64 d + 8)
    constexpr int LVT = 40;             // V^T row pitch     (32 keys + 8)
    constexpr int LPS = 40;             // P row pitch       (32 keys + 8)
    __shared__ bf16 Ks[2][32 * LKD];    // K tile  [32 keys][64 d], dbuf
    __shared__ bf16 Vt[2][64 * LVT];    // V^T tile [64 d][32 keys], dbuf
    __shared__ bf16 Ps[4][16 * LPS];    // per-wave P [16 q][32 keys]

    const int tid  = threadIdx.x;
    const int wave = tid >> 6, lane = tid & 63;
    const int quad = lane >> 4, l16 = lane & 15;
    const int bid = blockIdx.x;
    const int qt = 31 - (bid >> 6);              // heavy first
    const int hb = bid & 63;                     // head-block 0..63
    const int b = hb >> 4, h = hb & 15;
    const int q0 = qt * 64;

    const bf16* qbase  = qb + (size_t)b * T * Cc + h * HD;
    const bf16* kbase  = kb + (size_t)b * T * Cc + h * HD;
    const bf16* vthead = vtb + (size_t)(b * NH + h) * HD * T;
    bf16* yrow = y + (size_t)b * T * Cc + h * HD;

    // staging geometry (1 x b128 per lane per tile, each array)
    const int srK = tid >> 3, scK = (tid & 7) * 8;   // K: 32 rows x 8 chunks
    const int srV = tid >> 2, scV = (tid & 3) * 8;   // V^T: 64 rows x 4 chunks

    // ones B-frag for MFMA row sums
    bf16x8 ones;
#pragma unroll
    for (int e = 0; e < 8; ++e) ones[e] = (bf16)1.0f;

    // Q B-frag (n=l16 is q, k=dblk*32+quad*8+e is d), scale*log2e folded in
    bf16x8 qf[2];
    {
        int qrow = q0 + wave * 16 + l16;
#pragma unroll
        for (int dblk = 0; dblk < 2; ++dblk) {
            bf16x8 v = *(const bf16x8*)(qbase + (size_t)qrow * Cc + dblk * 32 + quad * 8);
#pragma unroll
            for (int e = 0; e < 8; ++e) v[e] = (bf16)((float)v[e] * 0.18033688f);
            qf[dblk] = v;
        }
    }

    f32x4 o[4] = {};           // O accum [d-chunk], C-layout (row=q, col=d)
    f32x4 osum = {};           // row-sum accum, same C-layout rows

    const int w0 = q0 + wave * 16;
    const int nt = q0 / 32 + 2;    // staged 32-key tiles

    // ---- prologue: load tile 0, commit to buf 0 ----
    bf16x8 kp = *(const bf16x8*)(kbase + (size_t)srK * Cc + scK);
    bf16x8 vp = *(const bf16x8*)(vthead + (size_t)srV * T + scV);
    *(bf16x8*)(&Ks[0][srK * LKD + scK]) = kp;
    *(bf16x8*)(&Vt[0][srV * LVT + scV]) = vp;

    int cur = 0;
    for (int it = 0; it < nt; ++it) {
        const int kt = it * 32;
        __syncthreads();   // buf[cur] writes visible; buf[cur^1] reads done

        // ---- issue next tile's global loads (in flight during compute) ----
        const bool more = (it + 1 < nt);
        if (more) {
            int ktn = kt + 32;
            kp = *(const bf16x8*)(kbase + (size_t)(ktn + srK) * Cc + scK);
            vp = *(const bf16x8*)(vthead + (size_t)srV * T + ktn + scV);
        }

        const bf16* ksc = Ks[cur];
        const bf16* vtc = Vt[cur];
        if (kt <= w0 + 15) {       // wave-level skip (no barrier inside)
            __builtin_amdgcn_s_setprio(1);
            // ---- S^T = K Q^T : [32 key][16 q] ----
            f32x4 st[2] = {};      // [km]
#pragma unroll
            for (int km = 0; km < 2; ++km) {
                bf16x8 kf0 = *(const bf16x8*)(&ksc[(km * 16 + l16) * LKD + quad * 8]);
                bf16x8 kf1 = *(const bf16x8*)(&ksc[(km * 16 + l16) * LKD + 32 + quad * 8]);
                st[km] = MFMA16(kf0, qf[0], st[km]);
                st[km] = MFMA16(kf1, qf[1], st[km]);
            }

            // ---- softmax numerator (lane holds 4 keys of one q) ----
            const bool needmask = (kt + 31 > w0);
            const int qrel = w0 + l16 - kt;   // q - kt
#pragma unroll
            for (int km = 0; km < 2; ++km)
#pragma unroll
                for (int r = 0; r < 4; ++r) {
                    float v = st[km][r];
                    if (needmask) {
                        int key = km * 16 + quad * 4 + r;
                        v = (key <= qrel) ? v : -INFINITY;
                    }
                    st[km][r] = __builtin_exp2f(v);
                }

            // ---- P -> per-wave LDS (b64 packs of 4 consecutive keys) ----
            bf16* pw = &Ps[wave][0];
#pragma unroll
            for (int km = 0; km < 2; ++km) {
                bf16x4 pk;
#pragma unroll
                for (int r = 0; r < 4; ++r) pk[r] = (bf16)st[km][r];
                *(bf16x4*)(&pw[l16 * LPS + km * 16 + quad * 4]) = pk;
            }
            // wave-local RAW: DS in-order per wave; compiler inserts lgkmcnt
            bf16x8 pf = *(const bf16x8*)(&pw[l16 * LPS + quad * 8]);

            // ---- O += P V (A=P m=q, B=V^T n=d); row sum via MFMA ----
#pragma unroll
            for (int dd = 0; dd < 4; ++dd) {
                bf16x8 vf = *(const bf16x8*)(&vtc[(dd * 16 + l16) * LVT + quad * 8]);
                o[dd] = MFMA16(pf, vf, o[dd]);
            }
            osum = MFMA16(pf, ones, osum);
            __builtin_amdgcn_s_setprio(0);
        }

        // ---- commit next tile to the other buffer (write-late) ----
        if (more) {
            *(bf16x8*)(&Ks[cur ^ 1][srK * LKD + scK]) = kp;
            *(bf16x8*)(&Vt[cur ^ 1][srV * LVT + scV]) = vp;
        }
        cur ^= 1;
    }

    // ---- epilogue: denominator is lane-local (osum rows == o rows) ----
#pragma unroll
    for (int r = 0; r < 4; ++r) {
        float inv = 1.0f / osum[r];
        int t = w0 + quad * 4 + r;
#pragma unroll
        for (int dd = 0; dd < 4; ++dd)
            yrow[(size_t)t * Cc + dd * 16 + l16] = (bf16)(o[dd][r] * inv);
    }
}

// ---------------------------------------------------------------------------
extern "C" void kernel_launch(void* const* d_in, const int* in_sizes, int n_in,
                              void* d_out, int out_size, void* d_ws, size_t ws_size,
                              hipStream_t stream) {
    const float* x      = (const float*)d_in[0];
    const float* W_attn = (const float*)d_in[1];
    const float* b_attn = (const float*)d_in[2];
    const float* W_proj = (const float*)d_in[3];
    const float* b_proj = (const float*)d_in[4];
    float* out = (float*)d_out;

    const int M = Bsz * T;             // 8192
    const size_t R = (size_t)M * Cc;   // 8.4M elems = 16 MiB bf16

    bf16* qb  = (bf16*)d_ws;        // R0
    bf16* kb  = qb + R;             // R1
    bf16* vtb = kb + R;             // R2 (written directly by gemm_qkv)
    bf16* xb  = vtb + R;            // R3: x in bf16, dead after gemm1
    bf16* yb  = xb;                 // R3: attn output overwrites xb
    bf16* WtA = (bf16*)d_out;       // parked in out (6 MiB), dead after gemm1
    bf16* WtP = qb;                 // parked in R0 after attention

    // 1. prep: x -> bf16 (R3)  +  W_attn^T -> WtA (parked in d_out)
    prep<<<4096 + 3072, 256, 0, stream>>>(x, xb, W_attn, WtA);
    // 2. qkv GEMM (256x128, 512 thr, swizzled LDS): q->qb, k->kb, v->vtb
    gemm_qkv<<<dim3(M / 256, C3 / 128), 512, 0, stream>>>(xb, WtA, b_attn, qb, kb, vtb, M, C3, Cc);
    // 3. attention (single 64-row q-tiles, heavy-first, XCD-local heads)
    attn_fused<<<2048, 256, 0, stream>>>(qb, kb, vtb, yb);
    // 4. W_proj^T -> WtP (R0, qb dead)
    transpose_f32_bf16<<<dim3(Cc / 32, Cc / 32), dim3(32, 8), 0, stream>>>(W_proj, WtP, Cc, Cc);
    // 5. out = yb @ W_proj + b_proj (fp32 out; overwrites parked WtA)
    gemm_bt<<<dim3(M / 128, Cc / 128), 256, 0, stream>>>(yb, WtP, b_proj, out, M, Cc, Cc);
}

// Round 8
// 249.187 us; speedup vs baseline: 2.4487x; 2.4487x over previous
//
#include <hip/hip_runtime.h>
#include <hip/hip_bf16.h>

// Problem: CausalSelfAttention  B=4, T=2048, C=1024, NH=16, HD=64
// Pipeline: prep (x->bf16 + W_attn^T, merged) -> QKV GEMM (256x128 tile,
// 512 thr, single-buf gload_lds, XOR-swizzled LDS via pre-swizzled global
// source, launch_bounds(512,4) -- (512,6) caused a VGPR-spill catastrophe
// in R7 -- fused V-transpose epilogue) -> MFMA flash causal attention v8
// (single 64-row q-tiles, grid 2048 heavy-first, 6 blocks/CU, dbuf K/V,
// MFMA row-sums, XCD-local heads) -> W_proj^T -> proj GEMM (128^2 dbuf).
//
// Workspace: 64 MiB in 4 regions of 16 MiB with lifetime overlap:
//   R0 qb   [8192][1024] bf16      live: gemm1 -> attn;  WtP parked here for gemm2
//   R1 kb   [8192][1024] bf16      live: gemm1 -> attn
//   R2 vtb  [B][NH][64][T] bf16    live: gemm1 (fused transpose) -> attn
//   R3 xb   [8192][1024] bf16      live: prep -> gemm1;  yb (attn out) overwrites
// d_out[0:6MiB] parks WtA (bf16 W_attn^T) until gemm1 done; gemm2 overwrites.

typedef __bf16 bf16;
typedef __bf16 bf16x4 __attribute__((ext_vector_type(4)));
typedef __bf16 bf16x8 __attribute__((ext_vector_type(8)));
typedef float  f32x4  __attribute__((ext_vector_type(4)));

#define MFMA16(a, b, c) __builtin_amdgcn_mfma_f32_16x16x32_bf16((a), (b), (c), 0, 0, 0)

// global -> LDS direct copy, 16B per lane. LDS dest is WAVE-UNIFORM base;
// HW adds lane*16B. Global src is per-lane.
#define GLOAD16(g, l)                                                 \
    __builtin_amdgcn_global_load_lds(                                 \
        (const __attribute__((address_space(1))) void*)(g),           \
        (__attribute__((address_space(3))) void*)(l), 16, 0, 0)

static constexpr int Bsz = 4;
static constexpr int T   = 2048;
static constexpr int Cc  = 1024;
static constexpr int NH  = 16;
static constexpr int HD  = 64;
static constexpr int C3  = 3 * Cc;   // 3072

// ---------------------------------------------------------------------------
// Prep kernel: blocks [0, 4096) convert x fp32 -> bf16 (8 elems/thread);
// blocks [4096, 4096+3072) transpose+downcast W_attn [1024][3072] -> WtA
// [3072][1024]. Both block types use 256 threads.
// ---------------------------------------------------------------------------
__global__ void prep(const float* __restrict__ x, bf16* __restrict__ xb,
                     const float* __restrict__ W_attn, bf16* __restrict__ WtA) {
    const int bid = blockIdx.x;
    const int tid = threadIdx.x;
    if (bid < 4096) {
        size_t i = ((size_t)bid * 256 + tid) * 8;
        f32x4 a0 = *(const f32x4*)(x + i);
        f32x4 a1 = *(const f32x4*)(x + i + 4);
        bf16x8 v;
#pragma unroll
        for (int e = 0; e < 4; ++e) { v[e] = (bf16)a0[e]; v[e + 4] = (bf16)a1[e]; }
        *(bf16x8*)(xb + i) = v;
    } else {
        __shared__ float tile[32][33];
        const int tb = bid - 4096;
        const int bx = (tb % (C3 / 32)) * 32;   // col base in W_attn (3072)
        const int by = (tb / (C3 / 32)) * 32;   // row base in W_attn (1024)
        const int tx = tid & 31, ty = tid >> 5; // (32, 8)
#pragma unroll
        for (int i = 0; i < 32; i += 8)
            tile[ty + i][tx] = W_attn[(size_t)(by + ty + i) * C3 + bx + tx];
        __syncthreads();
#pragma unroll
        for (int i = 0; i < 32; i += 8)
            WtA[(size_t)(bx + ty + i) * Cc + by + tx] = (bf16)tile[tx][ty + i];
    }
}

// ---------------------------------------------------------------------------
// 32x32 tiled transpose + downcast: in fp32 [R][Ccols] -> out bf16 [Ccols][R]
// (used for W_proj after attention frees R0)
// ---------------------------------------------------------------------------
__global__ void transpose_f32_bf16(const float* __restrict__ in, bf16* __restrict__ out,
                                   int R, int Ccols) {
    __shared__ float tile[32][33];
    int bx = blockIdx.x * 32;
    int by = blockIdx.y * 32;
    int tx = threadIdx.x, ty = threadIdx.y;  // block (32, 8)
#pragma unroll
    for (int i = 0; i < 32; i += 8)
        tile[ty + i][tx] = in[(size_t)(by + ty + i) * Ccols + bx + tx];
    __syncthreads();
#pragma unroll
    for (int i = 0; i < 32; i += 8)
        out[(size_t)(bx + ty + i) * R + by + tx] = (bf16)tile[tx][ty + i];
}

// ---------------------------------------------------------------------------
// GEMM1: qkv = xb(bf16) @ WtA^T + bias. 256x128 tile, 512 threads (8 waves,
// 4m x 2n, per-wave 64x64 output), single-buffered gload_lds staging,
// XOR-SWIZZLED LDS (T2, both-sides form):
//   gload_lds writes linearly, so the swizzle is applied by permuting the
//   GLOBAL source per lane: staged col16 = (lane&7) ^ (lane>>3)  (row&7 ==
//   lane>>3 for this geometry, constant across r and k0). Frag reads XOR
//   the 16B-chunk index with (l16&7): physical (row, c16) holds logical
//   col c16 ^ (row&7) on both sides -> involution, bijective, and lanes
//   0..15 spread over 8 slots -> 2-way max (free) instead of 16-way.
//   Verified R7: SQ_LDS_BANK_CONFLICT 18.9M -> 0.
// launch_bounds(512,4): VGPR 56, no spill (R6-measured). (512,6) forced
// VGPR 40 -> acc spill -> 2 GB/dispatch scratch traffic (R7). 2 blocks/CU.
// q/k thirds scattered to qo/ko [M][1024]; v third written TRANSPOSED per
// head directly to vt [B][NH][HD][T] (fused Tv).
// ---------------------------------------------------------------------------
__global__ __launch_bounds__(512, 4)
void gemm_qkv(const bf16* __restrict__ A, const bf16* __restrict__ Bt,
              const float* __restrict__ bias,
              bf16* __restrict__ qo, bf16* __restrict__ ko, bf16* __restrict__ vt,
              int M, int N, int K) {
    constexpr int BM = 256, BN = 128, BK = 64;
    __shared__ bf16 As[BM * BK];   // 32 KB
    __shared__ bf16 Bs[BN * BK];   // 16 KB

    const int tid  = threadIdx.x;
    const int wave = tid >> 6, lane = tid & 63;
    const int quad = lane >> 4, l16 = lane & 15;
    const int wm = wave >> 1, wn = wave & 1;     // 4m x 2n wave grid
    const int m0 = blockIdx.x * BM, n0 = blockIdx.y * BN;

    f32x4 acc[4][4] = {};

    // staging: thread's LDS slot is row = wave*8 + (lane>>3) + r*64,
    // c16 = lane&7 (16B chunks). Pre-swizzled global col16 = (lane&7)^(lane>>3).
    const int lrow = lane >> 3;
    const int lcol = ((lane & 7) ^ lrow) * 8;    // swizzled source column (elems)
    const bf16* Ab = A  + (size_t)(m0 + wave * 8 + lrow) * K + lcol;
    const bf16* Bb = Bt + (size_t)(n0 + wave * 8 + lrow) * K + lcol;
    const int wofs = wave * 512;
    const int sxo = l16 & 7;                     // read-side XOR (row&7)

    for (int k0 = 0; k0 < K; k0 += BK) {
#pragma unroll
        for (int r = 0; r < 4; ++r)
            GLOAD16(Ab + (size_t)(r * 64) * K + k0, As + wofs + r * 4096);
#pragma unroll
        for (int r = 0; r < 2; ++r)
            GLOAD16(Bb + (size_t)(r * 64) * K + k0, Bs + wofs + r * 4096);
        __syncthreads();   // drains vmcnt: tile ready

#pragma unroll
        for (int ks = 0; ks < 2; ++ks) {
            bf16x8 af[4], bfr[4];
#pragma unroll
            for (int i = 0; i < 4; ++i)
                af[i] = *(const bf16x8*)(&As[(wm * 64 + i * 16 + l16) * BK
                                             + (((ks * 4 + quad) ^ sxo) << 3)]);
#pragma unroll
            for (int j = 0; j < 4; ++j)
                bfr[j] = *(const bf16x8*)(&Bs[(wn * 64 + j * 16 + l16) * BK
                                              + (((ks * 4 + quad) ^ sxo) << 3)]);
#pragma unroll
            for (int i = 0; i < 4; ++i)
#pragma unroll
                for (int j = 0; j < 4; ++j)
                    acc[i][j] = MFMA16(af[i], bfr[j], acc[i][j]);
        }
        __syncthreads();   // all reads done before next stage
    }

    // epilogue: third = n0>>10 (BN=128 divides 1024 evenly)
    const int which = n0 >> 10;
    const int nc0 = n0 & 1023;
    if (which < 2) {
        bf16* dst = which ? ko : qo;
#pragma unroll
        for (int j = 0; j < 4; ++j) {
            int colg = n0 + wn * 64 + j * 16 + l16;
            int coll = nc0 + wn * 64 + j * 16 + l16;
            float bv = bias[colg];
#pragma unroll
            for (int i = 0; i < 4; ++i) {
                int rowb = m0 + wm * 64 + i * 16 + quad * 4;
#pragma unroll
                for (int r = 0; r < 4; ++r)
                    dst[(size_t)(rowb + r) * Cc + coll] = (bf16)(acc[i][j][r] + bv);
            }
        }
    } else {
        // v third: write transposed per head -> vt[b][h][d][t]; the 4 acc rows
        // per frag are consecutive t -> contiguous bf16x4 store.
#pragma unroll
        for (int j = 0; j < 4; ++j) {
            int colg = n0 + wn * 64 + j * 16 + l16;
            int coll = nc0 + wn * 64 + j * 16 + l16;
            int h = coll >> 6, d = coll & 63;
            float bv = bias[colg];
            bf16* vhead_d = vt + ((size_t)h * HD + d) * T;   // b-offset added below
#pragma unroll
            for (int i = 0; i < 4; ++i) {
                int rowb = m0 + wm * 64 + i * 16 + quad * 4;
                int b = rowb >> 11;          // T = 2048; BM=256 tiles never cross b
                int t = rowb & 2047;         // multiple of 4
                bf16x4 pk;
#pragma unroll
                for (int r = 0; r < 4; ++r) pk[r] = (bf16)(acc[i][j][r] + bv);
                *(bf16x4*)(vhead_d + (size_t)b * NH * HD * T + t) = pk;
            }
        }
    }
}

// ---------------------------------------------------------------------------
// GEMM2: out(fp32) = A(bf16) @ Bt^T + bias. 128^2 dbuf gload_lds (unchanged).
// ---------------------------------------------------------------------------
__global__ __launch_bounds__(256)
void gemm_bt(const bf16* __restrict__ A, const bf16* __restrict__ Bt,
             const float* __restrict__ bias, float* __restrict__ C,
             int M, int N, int K) {
    constexpr int BM = 128, BN = 128, BK = 64;
    __shared__ bf16 As[2][BM * BK];
    __shared__ bf16 Bs[2][BN * BK];

    const int tid  = threadIdx.x;
    const int wave = tid >> 6, lane = tid & 63;
    const int quad = lane >> 4, l16 = lane & 15;
    const int wm = wave & 1, wn = wave >> 1;
    const int m0 = blockIdx.x * BM, n0 = blockIdx.y * BN;

    f32x4 acc[4][4] = {};

    const int lrow = lane >> 3;
    const int lcol = (lane & 7) * 8;
    const bf16* Ab = A  + (size_t)(m0 + wave * 8 + lrow) * K + lcol;
    const bf16* Bb = Bt + (size_t)(n0 + wave * 8 + lrow) * K + lcol;
    const int wofs = wave * 512;

#pragma unroll
    for (int r = 0; r < 4; ++r) {
        GLOAD16(Ab + (size_t)r * 32 * K, As[0] + wofs + r * 2048);
        GLOAD16(Bb + (size_t)r * 32 * K, Bs[0] + wofs + r * 2048);
    }

    int cur = 0;
    for (int k0 = 0; k0 < K; k0 += BK) {
        __syncthreads();
        if (k0 + BK < K) {
#pragma unroll
            for (int r = 0; r < 4; ++r) {
                GLOAD16(Ab + (size_t)r * 32 * K + k0 + BK, As[cur ^ 1] + wofs + r * 2048);
                GLOAD16(Bb + (size_t)r * 32 * K + k0 + BK, Bs[cur ^ 1] + wofs + r * 2048);
            }
        }
        const bf16* Asc = As[cur];
        const bf16* Bsc = Bs[cur];
#pragma unroll
        for (int ks = 0; ks < 2; ++ks) {
            bf16x8 af[4], bfr[4];
#pragma unroll
            for (int i = 0; i < 4; ++i)
                af[i] = *(const bf16x8*)(&Asc[(wm * 64 + i * 16 + l16) * BK + ks * 32 + quad * 8]);
#pragma unroll
            for (int j = 0; j < 4; ++j)
                bfr[j] = *(const bf16x8*)(&Bsc[(wn * 64 + j * 16 + l16) * BK + ks * 32 + quad * 8]);
#pragma unroll
            for (int i = 0; i < 4; ++i)
#pragma unroll
                for (int j = 0; j < 4; ++j)
                    acc[i][j] = MFMA16(af[i], bfr[j], acc[i][j]);
        }
        cur ^= 1;
    }

#pragma unroll
    for (int j = 0; j < 4; ++j) {
        int col = n0 + wn * 64 + j * 16 + l16;
        float bv = bias[col];
#pragma unroll
        for (int i = 0; i < 4; ++i) {
            int rowb = m0 + wm * 64 + i * 16 + quad * 4;
#pragma unroll
            for (int r = 0; r < 4; ++r)
                C[(size_t)(rowb + r) * N + col] = acc[i][j][r] + bv;
        }
    }
}

// ---------------------------------------------------------------------------
// MFMA flash causal attention v8 (unchanged): single 64-row q-tile per block,
// grid 2048 heavy-first, 6 blocks/CU, dbuf K/V, 1 barrier/tile, MFMA
// row-sums, XCD-local heads, setprio on compute.
// ---------------------------------------------------------------------------
__global__ __launch_bounds__(256, 6)
void attn_fused(const bf16* __restrict__ qb, const bf16* __restrict__ kb,
                const bf16* __restrict__ vtb, bf16* __restrict__ y) {
    constexpr int LKD = 72;             // K-tile row pitch  (64 d + 8)
    constexpr int LVT = 40;             // V^T row pitch     (32 keys + 8)
    constexpr int LPS = 40;             // P row pitch       (32 keys + 8)
    __shared__ bf16 Ks[2][32 * LKD];    // K tile  [32 keys][64 d], dbuf
    __shared__ bf16 Vt[2][64 * LVT];    // V^T tile [64 d][32 keys], dbuf
    __shared__ bf16 Ps[4][16 * LPS];    // per-wave P [16 q][32 keys]

    const int tid  = threadIdx.x;
    const int wave = tid >> 6, lane = tid & 63;
    const int quad = lane >> 4, l16 = lane & 15;
    const int bid = blockIdx.x;
    const int qt = 31 - (bid >> 6);              // heavy first
    const int hb = bid & 63;                     // head-block 0..63
    const int b = hb >> 4, h = hb & 15;
    const int q0 = qt * 64;

    const bf16* qbase  = qb + (size_t)b * T * Cc + h * HD;
    const bf16* kbase  = kb + (size_t)b * T * Cc + h * HD;
    const bf16* vthead = vtb + (size_t)(b * NH + h) * HD * T;
    bf16* yrow = y + (size_t)b * T * Cc + h * HD;

    // staging geometry (1 x b128 per lane per tile, each array)
    const int srK = tid >> 3, scK = (tid & 7) * 8;   // K: 32 rows x 8 chunks
    const int srV = tid >> 2, scV = (tid & 3) * 8;   // V^T: 64 rows x 4 chunks

    // ones B-frag for MFMA row sums
    bf16x8 ones;
#pragma unroll
    for (int e = 0; e < 8; ++e) ones[e] = (bf16)1.0f;

    // Q B-frag (n=l16 is q, k=dblk*32+quad*8+e is d), scale*log2e folded in
    bf16x8 qf[2];
    {
        int qrow = q0 + wave * 16 + l16;
#pragma unroll
        for (int dblk = 0; dblk < 2; ++dblk) {
            bf16x8 v = *(const bf16x8*)(qbase + (size_t)qrow * Cc + dblk * 32 + quad * 8);
#pragma unroll
            for (int e = 0; e < 8; ++e) v[e] = (bf16)((float)v[e] * 0.18033688f);
            qf[dblk] = v;
        }
    }

    f32x4 o[4] = {};           // O accum [d-chunk], C-layout (row=q, col=d)
    f32x4 osum = {};           // row-sum accum, same C-layout rows

    const int w0 = q0 + wave * 16;
    const int nt = q0 / 32 + 2;    // staged 32-key tiles

    // ---- prologue: load tile 0, commit to buf 0 ----
    bf16x8 kp = *(const bf16x8*)(kbase + (size_t)srK * Cc + scK);
    bf16x8 vp = *(const bf16x8*)(vthead + (size_t)srV * T + scV);
    *(bf16x8*)(&Ks[0][srK * LKD + scK]) = kp;
    *(bf16x8*)(&Vt[0][srV * LVT + scV]) = vp;

    int cur = 0;
    for (int it = 0; it < nt; ++it) {
        const int kt = it * 32;
        __syncthreads();   // buf[cur] writes visible; buf[cur^1] reads done

        // ---- issue next tile's global loads (in flight during compute) ----
        const bool more = (it + 1 < nt);
        if (more) {
            int ktn = kt + 32;
            kp = *(const bf16x8*)(kbase + (size_t)(ktn + srK) * Cc + scK);
            vp = *(const bf16x8*)(vthead + (size_t)srV * T + ktn + scV);
        }

        const bf16* ksc = Ks[cur];
        const bf16* vtc = Vt[cur];
        if (kt <= w0 + 15) {       // wave-level skip (no barrier inside)
            __builtin_amdgcn_s_setprio(1);
            // ---- S^T = K Q^T : [32 key][16 q] ----
            f32x4 st[2] = {};      // [km]
#pragma unroll
            for (int km = 0; km < 2; ++km) {
                bf16x8 kf0 = *(const bf16x8*)(&ksc[(km * 16 + l16) * LKD + quad * 8]);
                bf16x8 kf1 = *(const bf16x8*)(&ksc[(km * 16 + l16) * LKD + 32 + quad * 8]);
                st[km] = MFMA16(kf0, qf[0], st[km]);
                st[km] = MFMA16(kf1, qf[1], st[km]);
            }

            // ---- softmax numerator (lane holds 4 keys of one q) ----
            const bool needmask = (kt + 31 > w0);
            const int qrel = w0 + l16 - kt;   // q - kt
#pragma unroll
            for (int km = 0; km < 2; ++km)
#pragma unroll
                for (int r = 0; r < 4; ++r) {
                    float v = st[km][r];
                    if (needmask) {
                        int key = km * 16 + quad * 4 + r;
                        v = (key <= qrel) ? v : -INFINITY;
                    }
                    st[km][r] = __builtin_exp2f(v);
                }

            // ---- P -> per-wave LDS (b64 packs of 4 consecutive keys) ----
            bf16* pw = &Ps[wave][0];
#pragma unroll
            for (int km = 0; km < 2; ++km) {
                bf16x4 pk;
#pragma unroll
                for (int r = 0; r < 4; ++r) pk[r] = (bf16)st[km][r];
                *(bf16x4*)(&pw[l16 * LPS + km * 16 + quad * 4]) = pk;
            }
            // wave-local RAW: DS in-order per wave; compiler inserts lgkmcnt
            bf16x8 pf = *(const bf16x8*)(&pw[l16 * LPS + quad * 8]);

            // ---- O += P V (A=P m=q, B=V^T n=d); row sum via MFMA ----
#pragma unroll
            for (int dd = 0; dd < 4; ++dd) {
                bf16x8 vf = *(const bf16x8*)(&vtc[(dd * 16 + l16) * LVT + quad * 8]);
                o[dd] = MFMA16(pf, vf, o[dd]);
            }
            osum = MFMA16(pf, ones, osum);
            __builtin_amdgcn_s_setprio(0);
        }

        // ---- commit next tile to the other buffer (write-late) ----
        if (more) {
            *(bf16x8*)(&Ks[cur ^ 1][srK * LKD + scK]) = kp;
            *(bf16x8*)(&Vt[cur ^ 1][srV * LVT + scV]) = vp;
        }
        cur ^= 1;
    }

    // ---- epilogue: denominator is lane-local (osum rows == o rows) ----
#pragma unroll
    for (int r = 0; r < 4; ++r) {
        float inv = 1.0f / osum[r];
        int t = w0 + quad * 4 + r;
#pragma unroll
        for (int dd = 0; dd < 4; ++dd)
            yrow[(size_t)t * Cc + dd * 16 + l16] = (bf16)(o[dd][r] * inv);
    }
}

// ---------------------------------------------------------------------------
extern "C" void kernel_launch(void* const* d_in, const int* in_sizes, int n_in,
                              void* d_out, int out_size, void* d_ws, size_t ws_size,
                              hipStream_t stream) {
    const float* x      = (const float*)d_in[0];
    const float* W_attn = (const float*)d_in[1];
    const float* b_attn = (const float*)d_in[2];
    const float* W_proj = (const float*)d_in[3];
    const float* b_proj = (const float*)d_in[4];
    float* out = (float*)d_out;

    const int M = Bsz * T;             // 8192
    const size_t R = (size_t)M * Cc;   // 8.4M elems = 16 MiB bf16

    bf16* qb  = (bf16*)d_ws;        // R0
    bf16* kb  = qb + R;             // R1
    bf16* vtb = kb + R;             // R2 (written directly by gemm_qkv)
    bf16* xb  = vtb + R;            // R3: x in bf16, dead after gemm1
    bf16* yb  = xb;                 // R3: attn output overwrites xb
    bf16* WtA = (bf16*)d_out;       // parked in out (6 MiB), dead after gemm1
    bf16* WtP = qb;                 // parked in R0 after attention

    // 1. prep: x -> bf16 (R3)  +  W_attn^T -> WtA (parked in d_out)
    prep<<<4096 + 3072, 256, 0, stream>>>(x, xb, W_attn, WtA);
    // 2. qkv GEMM (256x128, 512 thr, swizzled LDS): q->qb, k->kb, v->vtb
    gemm_qkv<<<dim3(M / 256, C3 / 128), 512, 0, stream>>>(xb, WtA, b_attn, qb, kb, vtb, M, C3, Cc);
    // 3. attention (single 64-row q-tiles, heavy-first, XCD-local heads)
    attn_fused<<<2048, 256, 0, stream>>>(qb, kb, vtb, yb);
    // 4. W_proj^T -> WtP (R0, qb dead)
    transpose_f32_bf16<<<dim3(Cc / 32, Cc / 32), dim3(32, 8), 0, stream>>>(W_proj, WtP, Cc, Cc);
    // 5. out = yb @ W_proj + b_proj (fp32 out; overwrites parked WtA)
    gemm_bt<<<dim3(M / 128, Cc / 128), 256, 0, stream>>>(yb, WtP, b_proj, out, M, Cc, Cc);
}